// Round 1
// baseline (790.970 us; speedup 1.0000x reference)
//
#include <hip/hip_runtime.h>
#include <hip/hip_bf16.h>
#include <stdint.h>

#define BB 4
#define SS 2048
#define DD 2048
#define HH 16
#define HD 128
#define MTOT (BB*SS)   // 8192 rows for both big GEMMs

typedef __attribute__((ext_vector_type(8))) short short8;   // 8 bf16 (4 VGPRs)
typedef __attribute__((ext_vector_type(4))) float f32x4;    // MFMA C/D

__device__ __forceinline__ unsigned short f2bf(float f) {
    union { float f; unsigned int u; } v; v.f = f;
    unsigned int u = v.u;
    return (unsigned short)((u + 0x7FFFu + ((u >> 16) & 1u)) >> 16);  // RNE
}

// ---------------------------------------------------------------- converts
__global__ __launch_bounds__(256) void convert_kernel(
    const float* __restrict__ src, unsigned short* __restrict__ dst, int n4) {
    int i = blockIdx.x * 256 + threadIdx.x;
    if (i >= n4) return;
    float4 v = ((const float4*)src)[i];
    unsigned int lo = (unsigned int)f2bf(v.x) | ((unsigned int)f2bf(v.y) << 16);
    unsigned int hi = (unsigned int)f2bf(v.z) | ((unsigned int)f2bf(v.w) << 16);
    ((uint2*)dst)[i] = make_uint2(lo, hi);
}

// RoPE on query + bf16 convert. One thread per (even,odd) pair.
__global__ __launch_bounds__(256) void rope_q_kernel(
    const float* __restrict__ q, const float* __restrict__ fc,
    const float* __restrict__ fs, unsigned short* __restrict__ dst) {
    int idx = blockIdx.x * 256 + threadIdx.x;          // pair index, 0..B*S*D/2
    int dpair = idx & (DD/2 - 1);                      // 0..1023
    int row   = idx >> 10;                             // b*S + s
    int s     = row & (SS - 1);
    int p     = dpair & 63;                            // pos within head /2
    float2 t = ((const float2*)q)[idx];
    float c = fc[s*64 + p], sn = fs[s*64 + p];
    float o1 = t.x*c - t.y*sn;
    float o2 = t.x*sn + t.y*c;
    ((unsigned int*)dst)[idx] = (unsigned int)f2bf(o1) | ((unsigned int)f2bf(o2) << 16);
}

// ---------------------------------------------------------------- GEMM
// C[m,n] = sum_k A[m,k]*W[n,k] + bias[n].  A: MxK bf16 row-major, W: NxK bf16.
// MODE 0: fused RoPE epilogue, bf16 out (K projection).
// MODE 1: plain epilogue, fp32 out (output projection).
template<int MODE>
__global__ __launch_bounds__(256, 2) void gemm_kernel(
    const unsigned short* __restrict__ A, const unsigned short* __restrict__ W,
    const float* __restrict__ bias, const float* __restrict__ fc,
    const float* __restrict__ fs, void* __restrict__ out)
{
    __shared__ unsigned short As[128*32];
    __shared__ unsigned short Bs[128*32];
    const int K = DD;
    int m0 = blockIdx.y * 128, n0 = blockIdx.x * 128;
    int t = threadIdx.x, lane = t & 63, w = t >> 6;
    int wm = w >> 1, wn = w & 1;
    int l15 = lane & 15, quad = lane >> 4;

    f32x4 acc[4][4] = {};

    for (int k0 = 0; k0 < K; k0 += 32) {
        __syncthreads();                    // prior tile's LDS reads done
        #pragma unroll
        for (int i = 0; i < 2; ++i) {
            int ci  = i*256 + t;            // 16B chunk id, 0..511
            int row = ci >> 2;
            int ce  = (ci & 3) * 8;         // elem offset within 32-col row
            const unsigned short* ga = A + (size_t)(m0 + row) * K + k0 + ce;
            const unsigned short* gb = W + (size_t)(n0 + row) * K + k0 + ce;
            unsigned short* la = As + (size_t)(i*256 + w*64) * 8;  // wave-uniform
            unsigned short* lb = Bs + (size_t)(i*256 + w*64) * 8;
            __builtin_amdgcn_global_load_lds(
                (__attribute__((address_space(1))) void*)(uintptr_t)ga,
                (__attribute__((address_space(3))) void*)la, 16, 0, 0);
            __builtin_amdgcn_global_load_lds(
                (__attribute__((address_space(1))) void*)(uintptr_t)gb,
                (__attribute__((address_space(3))) void*)lb, 16, 0, 0);
        }
        __syncthreads();                    // drains vmcnt (global_load_lds)

        short8 af[4], bw[4];
        #pragma unroll
        for (int i = 0; i < 4; ++i) {
            af[i] = *(const short8*)(As + (size_t)(wm*64 + i*16 + l15)*32 + quad*8);
            bw[i] = *(const short8*)(Bs + (size_t)(wn*64 + i*16 + l15)*32 + quad*8);
        }
        #pragma unroll
        for (int i = 0; i < 4; ++i)
            #pragma unroll
            for (int j = 0; j < 4; ++j)
                acc[i][j] = __builtin_amdgcn_mfma_f32_16x16x32_bf16(
                    af[i], bw[j], acc[i][j], 0, 0, 0);
    }

    // epilogue: C/D layout col=lane&15, row=quad*4+reg  [m89-verified]
    #pragma unroll
    for (int i = 0; i < 4; ++i) {
        #pragma unroll
        for (int j = 0; j < 4; ++j) {
            int col = n0 + wn*64 + j*16 + l15;
            float bv = bias[col];
            #pragma unroll
            for (int r = 0; r < 4; ++r) {
                int row = m0 + wm*64 + i*16 + quad*4 + r;
                float v = acc[i][j][r] + bv;
                if (MODE == 0) {
                    // fused RoPE: pair partner is the adjacent lane (col parity = lane parity)
                    int s = row & (SS - 1);
                    int p = (col & 127) >> 1;
                    float other = __shfl_xor(v, 1);
                    float c = fc[s*64 + p], sn = fs[s*64 + p];
                    float res = (col & 1) ? (other*sn + v*c) : (v*c - other*sn);
                    ((unsigned short*)out)[(size_t)row*DD + col] = f2bf(res);
                } else {
                    ((float*)out)[(size_t)row*DD + col] = v;
                }
            }
        }
    }
}

// ---------------------------------------------------------------- attention
// Flash-style causal attention. Block = 4 waves, 64 q-rows; wave owns 16 rows.
// Q/K/V are (B,S,H,HD) bf16; Q,K already RoPE'd.
__global__ __launch_bounds__(256, 2) void attn_kernel(
    const unsigned short* __restrict__ Q, const unsigned short* __restrict__ Kr,
    const unsigned short* __restrict__ V, unsigned short* __restrict__ O)
{
    constexpr int KSTR = 136;   // Qs/Ks row stride (pad: 272B = 17 banks-of-4 -> 2-way max)
    constexpr int VSTR = 72;    // VTs/Ps row stride (144B)
    __shared__ unsigned short Qs[64*KSTR];
    __shared__ unsigned short Ks[64*KSTR];
    __shared__ unsigned short VTs[128*VSTR];   // V transposed, XOR chunk-swizzled
    __shared__ unsigned short Ps[64*VSTR];

    int bh = blockIdx.y;
    int b = bh >> 4, h = bh & 15;
    int qt = (int)gridDim.x - 1 - (int)blockIdx.x;   // heavy (long) tiles first
    int q0 = qt * 64;
    size_t base = (size_t)b*SS*DD + (size_t)h*HD;    // + s*DD + d

    int t = threadIdx.x, lane = t & 63, w = t >> 6;
    int l15 = lane & 15, quad = lane >> 4;

    // stage Q once: 64 x 128, 16B chunks
    #pragma unroll
    for (int i = 0; i < 4; ++i) {
        int ci = i*256 + t;
        int row = ci >> 4, ce = (ci & 15) * 8;
        *(uint4*)(Qs + (size_t)row*KSTR + ce) =
            *(const uint4*)(Q + base + (size_t)(q0 + row)*DD + ce);
    }
    __syncthreads();

    short8 aq[4];
    #pragma unroll
    for (int kk = 0; kk < 4; ++kk)
        aq[kk] = *(const short8*)(Qs + (size_t)(w*16 + l15)*KSTR + kk*32 + quad*8);

    float m_i[4], l_i[4];
    #pragma unroll
    for (int r = 0; r < 4; ++r) { m_i[r] = -1e30f; l_i[r] = 0.f; }
    f32x4 o_acc[8] = {};

    const float scale = 0.08838834764831845f;   // 1/sqrt(128)

    for (int jt = 0; jt <= qt; ++jt) {
        int j0 = jt * 64;
        __syncthreads();                          // prior tile's Ks/VTs reads done
        // stage K tile (64 x 128)
        #pragma unroll
        for (int i = 0; i < 4; ++i) {
            int ci = i*256 + t;
            int row = ci >> 4, ce = (ci & 15) * 8;
            *(uint4*)(Ks + (size_t)row*KSTR + ce) =
                *(const uint4*)(Kr + base + (size_t)(j0 + row)*DD + ce);
        }
        // stage V transposed: VTs[d][s], chunk-of-8-s rotated by (d>>3)&7
        #pragma unroll
        for (int it = 0; it < 2; ++it) {
            int idx = t + it*256;                 // 0..511
            int dc = idx & 15;                    // d-chunk of 8 (coalesced dim)
            int s2 = idx >> 4;                    // s-pair 0..31
            uint4 u0 = *(const uint4*)(V + base + (size_t)(j0 + 2*s2)*DD + dc*8);
            uint4 u1 = *(const uint4*)(V + base + (size_t)(j0 + 2*s2 + 1)*DD + dc*8);
            unsigned int a[4] = {u0.x, u0.y, u0.z, u0.w};
            unsigned int c[4] = {u1.x, u1.y, u1.z, u1.w};
            int cs = s2 >> 2;                     // s-chunk index
            int wo = 2*(s2 & 3);                  // word offset within chunk (elems)
            int ch = (cs + dc) & 7;               // XOR-free rotation by dc
            #pragma unroll
            for (int jj = 0; jj < 4; ++jj) {
                int d0 = dc*8 + 2*jj;
                *(unsigned int*)(VTs + (size_t)d0*VSTR + ch*8 + wo) =
                    (a[jj] & 0xFFFFu) | ((c[jj] & 0xFFFFu) << 16);
                *(unsigned int*)(VTs + (size_t)(d0+1)*VSTR + ch*8 + wo) =
                    (a[jj] >> 16) | ((c[jj] >> 16) << 16);
            }
        }
        __syncthreads();

        // QK^T: wave's 16 q-rows x 64 k-cols
        f32x4 sacc[4];
        #pragma unroll
        for (int c = 0; c < 4; ++c) {
            sacc[c] = (f32x4){0.f, 0.f, 0.f, 0.f};
            #pragma unroll
            for (int kk = 0; kk < 4; ++kk) {
                short8 bk = *(const short8*)(Ks + (size_t)(c*16 + l15)*KSTR + kk*32 + quad*8);
                sacc[c] = __builtin_amdgcn_mfma_f32_16x16x32_bf16(aq[kk], bk, sacc[c], 0,0,0);
            }
        }

        // scale + causal mask + online softmax (rows quad*4+r owned by this wave)
        bool diag = (jt == qt);
        float p[4][4], mt[4];
        #pragma unroll
        for (int r = 0; r < 4; ++r) mt[r] = -1e30f;
        #pragma unroll
        for (int c = 0; c < 4; ++c)
            #pragma unroll
            for (int r = 0; r < 4; ++r) {
                float v = sacc[c][r] * scale;
                if (diag) {
                    int cg = j0 + c*16 + l15;
                    int rg = q0 + w*16 + quad*4 + r;
                    if (cg > rg) v = -1e30f;
                }
                p[c][r] = v;
                mt[r] = fmaxf(mt[r], v);
            }
        #pragma unroll
        for (int r = 0; r < 4; ++r) {           // row-max across the 16 lanes of the quad
            float m = mt[r];
            m = fmaxf(m, __shfl_xor(m, 1));
            m = fmaxf(m, __shfl_xor(m, 2));
            m = fmaxf(m, __shfl_xor(m, 4));
            m = fmaxf(m, __shfl_xor(m, 8));
            float mnew = fmaxf(m_i[r], m);
            mt[r] = __expf(m_i[r] - mnew);      // alpha
            m_i[r] = mnew;
        }
        float rs[4] = {0.f, 0.f, 0.f, 0.f};
        #pragma unroll
        for (int c = 0; c < 4; ++c)
            #pragma unroll
            for (int r = 0; r < 4; ++r) {
                float e = __expf(p[c][r] - m_i[r]);
                p[c][r] = e;
                rs[r] += e;
            }
        #pragma unroll
        for (int r = 0; r < 4; ++r) {
            float s = rs[r];
            s += __shfl_xor(s, 1);
            s += __shfl_xor(s, 2);
            s += __shfl_xor(s, 4);
            s += __shfl_xor(s, 8);
            l_i[r] = l_i[r]*mt[r] + s;
        }
        #pragma unroll
        for (int f = 0; f < 8; ++f)
            #pragma unroll
            for (int r = 0; r < 4; ++r)
                o_acc[f][r] *= mt[r];

        // P: C-layout -> LDS -> A-layout (m120-verified transform)
        #pragma unroll
        for (int c = 0; c < 4; ++c)
            #pragma unroll
            for (int r = 0; r < 4; ++r)
                Ps[(size_t)(w*16 + quad*4 + r)*VSTR + c*16 + l15] = f2bf(p[c][r]);
        __syncthreads();

        // PV: o += P(16x64) @ V(64x128)
        #pragma unroll
        for (int kk2 = 0; kk2 < 2; ++kk2) {
            short8 ap = *(const short8*)(Ps + (size_t)(w*16 + l15)*VSTR + kk2*32 + quad*8);
            #pragma unroll
            for (int f = 0; f < 8; ++f) {
                int d = f*16 + l15;
                int ch = ((kk2*4 + quad) + (d >> 3)) & 7;   // undo chunk rotation
                short8 bv = *(const short8*)(VTs + (size_t)d*VSTR + ch*8);
                o_acc[f] = __builtin_amdgcn_mfma_f32_16x16x32_bf16(ap, bv, o_acc[f], 0,0,0);
            }
        }
    }

    // epilogue: normalize and store bf16 (B,S,H,HD)
    #pragma unroll
    for (int f = 0; f < 8; ++f) {
        #pragma unroll
        for (int r = 0; r < 4; ++r) {
            int srow = q0 + w*16 + quad*4 + r;
            int d = f*16 + l15;
            O[base + (size_t)srow*DD + d] = f2bf(o_acc[f][r] / l_i[r]);
        }
    }
}

// ---------------------------------------------------------------- launch
extern "C" void kernel_launch(void* const* d_in, const int* in_sizes, int n_in,
                              void* d_out, int out_size, void* d_ws, size_t ws_size,
                              hipStream_t stream) {
    const float* x      = (const float*)d_in[0];
    const float* query  = (const float*)d_in[1];
    const float* value  = (const float*)d_in[2];
    const float* fc     = (const float*)d_in[3];
    const float* fs     = (const float*)d_in[4];
    const float* key_w  = (const float*)d_in[5];
    const float* key_b  = (const float*)d_in[6];
    const float* proj_w = (const float*)d_in[7];
    const float* proj_b = (const float*)d_in[8];

    const int ND  = BB*SS*DD;      // 16777216
    const int NW  = DD*DD;         // 4194304
    unsigned short* xb  = (unsigned short*)d_ws;   // x bf16
    unsigned short* kwb = xb  + ND;                // key_w bf16
    unsigned short* pwb = kwb + NW;                // proj_w bf16
    unsigned short* qr  = pwb + NW;                // query roped bf16
    unsigned short* vb  = qr  + ND;                // value bf16
    unsigned short* kr  = vb  + ND;                // k projected+roped bf16
    unsigned short* ao  = xb;                      // attn out reuses x region

    convert_kernel<<<ND/4/256, 256, 0, stream>>>(x, xb, ND/4);
    convert_kernel<<<NW/4/256, 256, 0, stream>>>(key_w, kwb, NW/4);
    convert_kernel<<<NW/4/256, 256, 0, stream>>>(proj_w, pwb, NW/4);
    convert_kernel<<<ND/4/256, 256, 0, stream>>>(value, vb, ND/4);
    rope_q_kernel<<<ND/2/256, 256, 0, stream>>>(query, fc, fs, qr);

    dim3 gg(DD/128, MTOT/128);     // 16 x 64
    gemm_kernel<0><<<gg, 256, 0, stream>>>(xb, kwb, key_b, fc, fs, (void*)kr);
    attn_kernel<<<dim3(SS/64, BB*HH), 256, 0, stream>>>(qr, kr, vb, ao);
    gemm_kernel<1><<<gg, 256, 0, stream>>>(ao, pwb, proj_b, nullptr, nullptr, d_out);
}